// Round 3
// baseline (800.122 us; speedup 1.0000x reference)
//
#include <hip/hip_runtime.h>

typedef unsigned short u16;
typedef unsigned int   u32;
typedef __attribute__((ext_vector_type(8))) short short8;
typedef __attribute__((ext_vector_type(4))) float f32x4;

__device__ __forceinline__ float b2f(u16 u) { return __uint_as_float(((u32)u) << 16); }
__device__ __forceinline__ u16 f2b(float f) {
    u32 i = __float_as_uint(f);
    return (u16)((i + 0x7FFFu + ((i >> 16) & 1u)) >> 16);   // RNE
}
__device__ __forceinline__ float gelu_f(float v) {
    return 0.5f * v * (1.f + erff(v * 0.70710678118654752f));  // exact-erf GELU
}
// mode-aware scalar float load: f32 ? fp32 : bf16
__device__ __forceinline__ float ldf(const void* p, int i, int f32) {
    return f32 ? ((const float*)p)[i] : b2f(((const u16*)p)[i]);
}

// ---------------- dtype probe (one wave, ballot-parallel) ----------------
// mode[0]=1 if edge_index is int64; mode[1]=1 if float tensors are fp32
__global__ void probe_kernel(const int* __restrict__ ei, const u16* __restrict__ xw,
                             int* __restrict__ mode) {
    int lane = threadIdx.x;  // 64 threads
    int v = (lane < 8) ? ei[2 * lane + 1] : 0;
    unsigned long long nz = __ballot(v != 0);
    u16 h = xw[2 * lane];
    int e = (h >> 7) & 0xFF;
    unsigned long long pl = __ballot(e >= 100 && e <= 140);
    if (lane == 0) {
        mode[0] = (nz == 0ULL) ? 1 : 0;
        mode[1] = (__popcll(pl) >= 48) ? 0 : 1;
    }
}

// ---------------- fallback (ws too small): out = alpha*rr ----------------
__global__ __launch_bounds__(256) void fallback_kernel(const void* __restrict__ rr,
                                                       const void* __restrict__ al,
                                                       const int* __restrict__ mode,
                                                       void* __restrict__ out, int N) {
    int i = blockIdx.x * 256 + threadIdx.x;
    if (i >= N) return;
    int f32 = mode ? mode[1] : 0;
    float a = 1.f / (1.f + expf(-ldf(al, 0, f32)));
    float v = a * ldf(rr, i, f32);
    if (f32) ((float*)out)[i] = v; else ((u16*)out)[i] = f2b(v);
}

// ---------------- CSR build ----------------
__global__ __launch_bounds__(256) void hist_kernel(const int* __restrict__ ei, int E, int N,
                                                   const int* __restrict__ mode,
                                                   int* __restrict__ deg) {
    int i = blockIdx.x * 256 + threadIdx.x;
    if (i >= E) return;
    int m64 = mode[0];
    int d = m64 ? ei[2 * E + 2 * i] : ei[E + i];
    if ((unsigned)d < (unsigned)N) atomicAdd(&deg[d], 1);
}

__global__ __launch_bounds__(256) void scanA_kernel(const int* __restrict__ deg,
                                                    int* __restrict__ part) {
    int t = threadIdx.x, lane = t & 63, wv = t >> 6;
    size_t base = (size_t)blockIdx.x * 2048 + (size_t)t * 8;
    int s = 0;
#pragma unroll
    for (int j = 0; j < 8; j++) s += deg[base + j];
    for (int m = 1; m < 64; m <<= 1) s += __shfl_xor(s, m, 64);
    __shared__ int ws4[4];
    if (lane == 0) ws4[wv] = s;
    __syncthreads();
    if (t == 0) part[blockIdx.x] = ws4[0] + ws4[1] + ws4[2] + ws4[3];
}

__global__ void scanB_kernel(int* __restrict__ part, int nb) {
    int lane = threadIdx.x;
    int v = (lane < nb) ? part[lane] : 0;
    int orig = v;
    for (int d = 1; d < 64; d <<= 1) {
        int o = __shfl_up(v, d, 64);
        if (lane >= d) v += o;
    }
    if (lane < nb) part[lane] = v - orig;  // exclusive
}

__global__ __launch_bounds__(256) void scanC_kernel(const int* __restrict__ deg,
                                                    const int* __restrict__ part,
                                                    int* __restrict__ off) {
    int t = threadIdx.x, lane = t & 63, wv = t >> 6;
    size_t base = (size_t)blockIdx.x * 2048 + (size_t)t * 8;
    int v[8];
    int s = 0;
#pragma unroll
    for (int j = 0; j < 8; j++) { v[j] = deg[base + j]; s += v[j]; }
    int incl = s;
    for (int d = 1; d < 64; d <<= 1) {
        int o = __shfl_up(incl, d, 64);
        if (lane >= d) incl += o;
    }
    __shared__ int wsum[4];
    if (lane == 63) wsum[wv] = incl;
    __syncthreads();
    int pre = part[blockIdx.x] + (incl - s);
    for (int w = 0; w < wv; w++) pre += wsum[w];
#pragma unroll
    for (int j = 0; j < 8; j++) { off[base + j] = pre; pre += v[j]; }
    if (blockIdx.x == gridDim.x - 1 && t == 255) off[base + 8] = pre;  // off[NP]
}

__global__ __launch_bounds__(256) void fill_kernel(const int* __restrict__ ei, int E, int N,
                                                   const int* __restrict__ mode,
                                                   const int* __restrict__ off,
                                                   int* __restrict__ cur,
                                                   int* __restrict__ sorted) {
    int i = blockIdx.x * 256 + threadIdx.x;
    if (i >= E) return;
    int m64 = mode[0];
    int s = m64 ? ei[2 * i] : ei[i];
    int d = m64 ? ei[2 * E + 2 * i] : ei[E + i];
    if ((unsigned)d >= (unsigned)N) return;
    if ((unsigned)s >= (unsigned)N) s = 0;
    int p = atomicAdd(&cur[d], 1);
    int pos = off[d] + p;
    if ((unsigned)pos < (unsigned)E) sorted[pos] = s;
}

// ---------------- weight transpose into bf16 T ----------------
// T layout: [0]=Wp^T [16384]=Wl0^T [32768]=Wr0^T [49152]=Wl1^T [65536]=Wr1^T [81920]=Ws1^T(64x128)
__global__ __launch_bounds__(256) void prep_kernel(const void* __restrict__ Wp, const void* __restrict__ Wl0,
                                                   const void* __restrict__ Wr0, const void* __restrict__ Wl1,
                                                   const void* __restrict__ Wr1, const void* __restrict__ Ws1,
                                                   const int* __restrict__ mode, u16* __restrict__ T) {
    int idx = blockIdx.x * 256 + threadIdx.x;
    int f32 = mode[1];
    if (idx < 81920) {
        int m = idx >> 14, e = idx & 16383, n = e & 127, k = e >> 7;
        const void* s;
        switch (m) {
            case 0: s = Wp; break;
            case 1: s = Wl0; break;
            case 2: s = Wr0; break;
            case 3: s = Wl1; break;
            default: s = Wr1; break;
        }
        float v = ldf(s, e, f32);
        T[m * 16384 + n * 128 + k] = f2b(v);
    } else if (idx < 90112) {
        int e = idx - 81920, k = e >> 6, n = e & 63;
        T[81920 + n * 128 + k] = f2b(ldf(Ws1, e, f32));
    }
}

// ---------------- aggregation: mean over CSR neighbors ----------------
// bf16 fast path: one wave per node; lane = (edge-slot sub=lane>>4, dim-group m=lane&15).
// Each dwordx4 gather brings 4 edges x 16B = 1KB/wave-instruction; 2 in flight (8 edges/iter).
__device__ __forceinline__ void acc8(float* acc, uint4 v) {
    acc[0] += b2f((u16)v.x); acc[1] += b2f((u16)(v.x >> 16));
    acc[2] += b2f((u16)v.y); acc[3] += b2f((u16)(v.y >> 16));
    acc[4] += b2f((u16)v.z); acc[5] += b2f((u16)(v.z >> 16));
    acc[6] += b2f((u16)v.w); acc[7] += b2f((u16)(v.w >> 16));
}

__global__ __launch_bounds__(256) void agg_kernel(const void* __restrict__ Hv, const int* __restrict__ off,
                                                  const int* __restrict__ srcs, u16* __restrict__ meanO,
                                                  int N, int E, const int* __restrict__ mode, int applyF32) {
    const int tid = threadIdx.x;
    const int node = blockIdx.x * 4 + (tid >> 6);
    if (node >= N) return;
    const int lane = tid & 63;
    int s0 = off[node], s1 = off[node + 1];
    if (s0 < 0) s0 = 0;
    if (s1 > E) s1 = E;
    if (s1 < s0) s1 = s0;
    const int dg = s1 - s0;
    const float inv = 1.f / (float)(dg > 1 ? dg : 1);
    const int f32 = applyF32 ? mode[1] : 0;
    if (!f32) {
        const u16* H = (const u16*)Hv;
        const int sub = lane >> 4, m = lane & 15;
        float acc[8];
#pragma unroll
        for (int d = 0; d < 8; d++) acc[d] = 0.f;
        for (int e = s0; e < s1; e += 8) {
            int ee0 = e + sub, ee1 = ee0 + 4;
            bool ok0 = ee0 < s1, ok1 = ee1 < s1;
            int i0 = srcs[ok0 ? ee0 : s0];
            int i1 = srcs[ok1 ? ee1 : s0];
            if ((unsigned)i0 >= (unsigned)N) i0 = 0;
            if ((unsigned)i1 >= (unsigned)N) i1 = 0;
            uint4 v0 = *(const uint4*)(H + (size_t)i0 * 128 + m * 8);
            uint4 v1 = *(const uint4*)(H + (size_t)i1 * 128 + m * 8);
            if (ok0) acc8(acc, v0);
            if (ok1) acc8(acc, v1);
        }
#pragma unroll
        for (int d = 0; d < 8; d++) {
            acc[d] += __shfl_xor(acc[d], 16, 64);
            acc[d] += __shfl_xor(acc[d], 32, 64);
        }
        if (sub == 0) {
            uint4 o;
            o.x = (u32)f2b(acc[0] * inv) | ((u32)f2b(acc[1] * inv) << 16);
            o.y = (u32)f2b(acc[2] * inv) | ((u32)f2b(acc[3] * inv) << 16);
            o.z = (u32)f2b(acc[4] * inv) | ((u32)f2b(acc[5] * inv) << 16);
            o.w = (u32)f2b(acc[6] * inv) | ((u32)f2b(acc[7] * inv) << 16);
            *(uint4*)(meanO + (size_t)node * 128 + m * 8) = o;
        }
    } else {
        // fp32 input path (cold; only if probe says fp32): 2 dims/lane scalar walk
        const float* Hf = (const float*)Hv;
        int col = lane * 2;
        float r0 = 0.f, r1 = 0.f;
        for (int e = s0; e < s1; ++e) {
            int iA = srcs[e];
            if ((unsigned)iA >= (unsigned)N) iA = 0;
            const float* p = Hf + (size_t)iA * 128 + col;
            r0 += p[0]; r1 += p[1];
        }
        *(u32*)(meanO + (size_t)node * 128 + col) = (u32)f2b(r0 * inv) | ((u32)f2b(r1 * inv) << 16);
    }
}

// ---------------- MFMA GEMM pieces ----------------
// A row-major [row][k] (bf16 or fp32 per flag), WT bf16 [n][k]; wave: 32 rows x 128 cols.
__device__ __forceinline__ short8 load_frag(const void* A, size_t elemIdx, int f32) {
    if (!f32) return *(const short8*)((const u16*)A + elemIdx);
    const float* f = (const float*)A + elemIdx;
    short8 r;
#pragma unroll
    for (int j = 0; j < 8; j++) r[j] = (short)f2b(f[j]);
    return r;
}

__device__ __forceinline__ void mm_product(const void* A, const u16* __restrict__ WT,
                                           long rowBase, int N, int m0, int q, int aF32,
                                           f32x4 acc[2][8]) {
#pragma unroll
    for (int ks = 0; ks < 4; ++ks) {
        const int k = ks * 32 + q * 8;
        short8 bf[8];
#pragma unroll
        for (int n = 0; n < 8; n++) bf[n] = *(const short8*)(WT + (n * 16 + m0) * 128 + k);
#pragma unroll
        for (int r = 0; r < 2; r++) {
            long row = rowBase + r * 16 + m0;
            if (row >= N) row = N - 1;
            short8 a = load_frag(A, (size_t)row * 128 + k, aF32);
#pragma unroll
            for (int n = 0; n < 8; n++)
                acc[r][n] = __builtin_amdgcn_mfma_f32_16x16x32_bf16(a, bf[n], acc[r][n], 0, 0, 0);
        }
    }
}

// h0 = gelu(mean@Wl0 + x@Wr0 + bl0) + x@Wp + bp     (h0 always bf16)
__global__ __launch_bounds__(256) void gemm0_kernel(const void* __restrict__ x, const u16* __restrict__ mean,
                                                    const u16* __restrict__ WTl, const u16* __restrict__ WTr,
                                                    const u16* __restrict__ WTp, const void* __restrict__ bl,
                                                    const void* __restrict__ bp, const int* __restrict__ mode,
                                                    u16* __restrict__ h0, int N) {
    const int lane = threadIdx.x & 63, wave = threadIdx.x >> 6;
    const int m0 = lane & 15, q = lane >> 4;
    const int f32 = mode[1];
    const long rowBase = (long)blockIdx.x * 128 + wave * 32;
    f32x4 accU[2][8], accR[2][8];
#pragma unroll
    for (int r = 0; r < 2; r++)
#pragma unroll
        for (int n = 0; n < 8; n++) { accU[r][n] = {0.f, 0.f, 0.f, 0.f}; accR[r][n] = {0.f, 0.f, 0.f, 0.f}; }
    mm_product(mean, WTl, rowBase, N, m0, q, 0, accU);
    mm_product(x, WTr, rowBase, N, m0, q, f32, accU);
    mm_product(x, WTp, rowBase, N, m0, q, f32, accR);
#pragma unroll
    for (int r = 0; r < 2; r++)
#pragma unroll
        for (int n = 0; n < 8; n++) {
            int col = n * 16 + m0;
            float blv = ldf(bl, col, f32), bpv = ldf(bp, col, f32);
#pragma unroll
            for (int g = 0; g < 4; g++) {
                long row = rowBase + r * 16 + q * 4 + g;
                if (row < N) {
                    float u = accU[r][n][g] + blv;
                    float h = gelu_f(u) + accR[r][n][g] + bpv;
                    h0[(size_t)row * 128 + col] = f2b(h);
                }
            }
        }
}

// h1 = gelu(mean1@Wl1 + h0@Wr1 + bl1) + h0   (mean/h1 may alias: waves touch only own rows)
__global__ __launch_bounds__(256) void gemm1_kernel(const u16* __restrict__ h0, const u16* mean,
                                                    const u16* __restrict__ WTl, const u16* __restrict__ WTr,
                                                    const void* __restrict__ bl, const int* __restrict__ mode,
                                                    u16* h1, int N) {
    const int lane = threadIdx.x & 63, wave = threadIdx.x >> 6;
    const int m0 = lane & 15, q = lane >> 4;
    const int f32 = mode[1];
    const long rowBase = (long)blockIdx.x * 128 + wave * 32;
    f32x4 accU[2][8];
#pragma unroll
    for (int r = 0; r < 2; r++)
#pragma unroll
        for (int n = 0; n < 8; n++) accU[r][n] = {0.f, 0.f, 0.f, 0.f};
    mm_product(mean, WTl, rowBase, N, m0, q, 0, accU);
    mm_product(h0, WTr, rowBase, N, m0, q, 0, accU);
#pragma unroll
    for (int r = 0; r < 2; r++)
#pragma unroll
        for (int n = 0; n < 8; n++) {
            int col = n * 16 + m0;
            float blv = ldf(bl, col, f32);
#pragma unroll
            for (int g = 0; g < 4; g++) {
                long row = rowBase + r * 16 + q * 4 + g;
                if (row < N) {
                    float res = b2f(h0[(size_t)row * 128 + col]);
                    float h = gelu_f(accU[r][n][g] + blv) + res;
                    h1[(size_t)row * 128 + col] = f2b(h);
                }
            }
        }
}

// out = alpha*rr + (1-alpha)*(gelu(h1@Ws1+bs1)@Ws2 + bs2)
__global__ __launch_bounds__(256) void score_kernel(const u16* __restrict__ h1, const u16* __restrict__ WTs,
                                                    const void* __restrict__ bs1, const void* __restrict__ w2,
                                                    const void* __restrict__ bs2, const void* __restrict__ rr,
                                                    const void* __restrict__ alpha_p, const int* __restrict__ mode,
                                                    void* __restrict__ out, int N) {
    const int lane = threadIdx.x & 63, wave = threadIdx.x >> 6;
    const int m0 = lane & 15, q = lane >> 4;
    const int f32 = mode[1];
    const long rowBase = (long)blockIdx.x * 128 + wave * 32;
    f32x4 acc[2][4];
#pragma unroll
    for (int r = 0; r < 2; r++)
#pragma unroll
        for (int n = 0; n < 4; n++) acc[r][n] = {0.f, 0.f, 0.f, 0.f};
#pragma unroll
    for (int ks = 0; ks < 4; ++ks) {
        const int k = ks * 32 + q * 8;
        short8 bf[4];
#pragma unroll
        for (int n = 0; n < 4; n++) bf[n] = *(const short8*)(WTs + (n * 16 + m0) * 128 + k);
#pragma unroll
        for (int r = 0; r < 2; r++) {
            long row = rowBase + r * 16 + m0;
            if (row >= N) row = N - 1;
            short8 a = *(const short8*)(h1 + (size_t)row * 128 + k);
#pragma unroll
            for (int n = 0; n < 4; n++)
                acc[r][n] = __builtin_amdgcn_mfma_f32_16x16x32_bf16(a, bf[n], acc[r][n], 0, 0, 0);
        }
    }
    float alpha = 1.f / (1.f + expf(-ldf(alpha_p, 0, f32)));
    float bs2v = ldf(bs2, 0, f32);
    float w2v[4], b1v[4];
#pragma unroll
    for (int n = 0; n < 4; n++) {
        int col = n * 16 + m0;
        w2v[n] = ldf(w2, col, f32);
        b1v[n] = ldf(bs1, col, f32);
    }
#pragma unroll
    for (int r = 0; r < 2; r++) {
        float s[4] = {0.f, 0.f, 0.f, 0.f};
#pragma unroll
        for (int n = 0; n < 4; n++)
#pragma unroll
            for (int g = 0; g < 4; g++) s[g] += gelu_f(acc[r][n][g] + b1v[n]) * w2v[n];
#pragma unroll
        for (int g = 0; g < 4; g++) {
            s[g] += __shfl_xor(s[g], 1, 64);
            s[g] += __shfl_xor(s[g], 2, 64);
            s[g] += __shfl_xor(s[g], 4, 64);
            s[g] += __shfl_xor(s[g], 8, 64);
        }
        if (m0 == 0) {
            long row0 = rowBase + r * 16 + q * 4;
#pragma unroll
            for (int g = 0; g < 4; g++) {
                long row = row0 + g;
                if (row < N) {
                    float sc = s[g] + bs2v;
                    float v = alpha * ldf(rr, (int)row, f32) + (1.f - alpha) * sc;
                    if (f32) ((float*)out)[row] = v; else ((u16*)out)[row] = f2b(v);
                }
            }
        }
    }
}

extern "C" void kernel_launch(void* const* d_in, const int* in_sizes, int n_in,
                              void* d_out, int out_size, void* d_ws, size_t ws_size,
                              hipStream_t stream) {
    const void* x = d_in[0];
    const int* ei = (const int*)d_in[1];
    const void* rr = d_in[2];
    const void* Wp = d_in[3];
    const void* bp = d_in[4];
    const void* Wl0 = d_in[5];
    const void* bl0 = d_in[6];
    const void* Wr0 = d_in[7];
    const void* Wl1 = d_in[8];
    const void* bl1 = d_in[9];
    const void* Wr1 = d_in[10];
    const void* Ws1 = d_in[11];
    const void* bs1 = d_in[12];
    const void* Ws2 = d_in[13];
    const void* bs2 = d_in[14];
    const void* alpha = d_in[15];

    const int N = in_sizes[0] / 128;
    const int E = in_sizes[1] / 2;
    const int NP = ((N + 2047) / 2048) * 2048;
    const int NB = NP / 2048;

    char* w = (char*)d_ws;
    size_t used = 0;
    auto alloc = [&](size_t b) { char* p = w + used; used += (b + 255) & ~(size_t)255; return p; };
    int* mode = (int*)alloc(256);
    int* deg = (int*)alloc((size_t)NP * 4);
    int* cursor = (int*)alloc((size_t)NP * 4);   // contiguous with deg
    int* off = (int*)alloc((size_t)(NP + 64) * 4);
    int* part = (int*)alloc(64 * 4);
    int* sorted = (int*)alloc((size_t)E * 4);
    u16* T = (u16*)alloc(90112 * 2);
    u16* meanb = (u16*)alloc((size_t)NP * 128 * 2);
    u16* h0 = (u16*)alloc((size_t)NP * 128 * 2);
    u16* h1 = meanb;  // alias: gemm1 waves read/write only their own 32-row slices

    if (ws_size < 4096) {
        fallback_kernel<<<(N + 255) / 256, 256, 0, stream>>>(rr, alpha, nullptr, d_out, N);
        return;
    }
    probe_kernel<<<1, 64, 0, stream>>>(ei, (const u16*)x, mode);
    if (used > ws_size) {
        fallback_kernel<<<(N + 255) / 256, 256, 0, stream>>>(rr, alpha, mode, d_out, N);
        return;
    }

    hipMemsetAsync(deg, 0, (size_t)NP * 4 * 2, stream);      // deg + cursor

    prep_kernel<<<(90112 + 255) / 256, 256, 0, stream>>>(Wp, Wl0, Wr0, Wl1, Wr1, Ws1, mode, T);
    hist_kernel<<<(E + 255) / 256, 256, 0, stream>>>(ei, E, N, mode, deg);
    scanA_kernel<<<NB, 256, 0, stream>>>(deg, part);
    scanB_kernel<<<1, 64, 0, stream>>>(part, NB);
    scanC_kernel<<<NB, 256, 0, stream>>>(deg, part, off);
    fill_kernel<<<(E + 255) / 256, 256, 0, stream>>>(ei, E, N, mode, off, cursor, sorted);

    const int gemmGrid = (N + 127) / 128;
    const int aggGrid = (N + 3) / 4;

    agg_kernel<<<aggGrid, 256, 0, stream>>>(x, off, sorted, meanb, N, E, mode, 1);
    gemm0_kernel<<<gemmGrid, 256, 0, stream>>>(x, meanb, T + 16384, T + 32768, T + 0, bl0, bp, mode, h0, N);
    agg_kernel<<<aggGrid, 256, 0, stream>>>(h0, off, sorted, meanb, N, E, mode, 0);
    gemm1_kernel<<<gemmGrid, 256, 0, stream>>>(h0, meanb, T + 49152, T + 65536, bl1, mode, h1, N);
    score_kernel<<<gemmGrid, 256, 0, stream>>>(h1, T + 81920, bs1, Ws2, bs2, rr, alpha, mode, d_out, N);
}

// Round 4
// 682.622 us; speedup vs baseline: 1.1721x; 1.1721x over previous
//
#include <hip/hip_runtime.h>

typedef unsigned short u16;
typedef unsigned int   u32;
typedef __attribute__((ext_vector_type(8))) short short8;
typedef __attribute__((ext_vector_type(4))) float f32x4;

__device__ __forceinline__ float b2f(u16 u) { return __uint_as_float(((u32)u) << 16); }
__device__ __forceinline__ u16 f2b(float f) {
    u32 i = __float_as_uint(f);
    return (u16)((i + 0x7FFFu + ((i >> 16) & 1u)) >> 16);   // RNE
}
__device__ __forceinline__ float gelu_f(float v) {
    return 0.5f * v * (1.f + erff(v * 0.70710678118654752f));  // exact-erf GELU
}
// mode-aware scalar float load: f32 ? fp32 : bf16
__device__ __forceinline__ float ldf(const void* p, int i, int f32) {
    return f32 ? ((const float*)p)[i] : b2f(((const u16*)p)[i]);
}

// ---------------- dtype probe (one wave, ballot-parallel) ----------------
__global__ void probe_kernel(const int* __restrict__ ei, const u16* __restrict__ xw,
                             int* __restrict__ mode) {
    int lane = threadIdx.x;  // 64 threads
    int v = (lane < 8) ? ei[2 * lane + 1] : 0;
    unsigned long long nz = __ballot(v != 0);
    u16 h = xw[2 * lane];
    int e = (h >> 7) & 0xFF;
    unsigned long long pl = __ballot(e >= 100 && e <= 140);
    if (lane == 0) {
        mode[0] = (nz == 0ULL) ? 1 : 0;
        mode[1] = (__popcll(pl) >= 48) ? 0 : 1;
    }
}

// ---------------- fallback (ws too small): out = alpha*rr ----------------
__global__ __launch_bounds__(256) void fallback_kernel(const void* __restrict__ rr,
                                                       const void* __restrict__ al,
                                                       const int* __restrict__ mode,
                                                       void* __restrict__ out, int N) {
    int i = blockIdx.x * 256 + threadIdx.x;
    if (i >= N) return;
    int f32 = mode ? mode[1] : 0;
    float a = 1.f / (1.f + expf(-ldf(al, 0, f32)));
    float v = a * ldf(rr, i, f32);
    if (f32) ((float*)out)[i] = v; else ((u16*)out)[i] = f2b(v);
}

// ---------------- CSR build ----------------
__global__ __launch_bounds__(256) void hist_kernel(const int* __restrict__ ei, int E, int N,
                                                   const int* __restrict__ mode,
                                                   int* __restrict__ deg) {
    int i = blockIdx.x * 256 + threadIdx.x;
    if (i >= E) return;
    int m64 = mode[0];
    int d = m64 ? ei[2 * E + 2 * i] : ei[E + i];
    if ((unsigned)d < (unsigned)N) atomicAdd(&deg[d], 1);
}

__global__ __launch_bounds__(256) void scanA_kernel(const int* __restrict__ deg,
                                                    int* __restrict__ part) {
    int t = threadIdx.x, lane = t & 63, wv = t >> 6;
    size_t base = (size_t)blockIdx.x * 2048 + (size_t)t * 8;
    int s = 0;
#pragma unroll
    for (int j = 0; j < 8; j++) s += deg[base + j];
    for (int m = 1; m < 64; m <<= 1) s += __shfl_xor(s, m, 64);
    __shared__ int ws4[4];
    if (lane == 0) ws4[wv] = s;
    __syncthreads();
    if (t == 0) part[blockIdx.x] = ws4[0] + ws4[1] + ws4[2] + ws4[3];
}

__global__ void scanB_kernel(int* __restrict__ part, int nb) {
    int lane = threadIdx.x;
    int v = (lane < nb) ? part[lane] : 0;
    int orig = v;
    for (int d = 1; d < 64; d <<= 1) {
        int o = __shfl_up(v, d, 64);
        if (lane >= d) v += o;
    }
    if (lane < nb) part[lane] = v - orig;  // exclusive
}

__global__ __launch_bounds__(256) void scanC_kernel(const int* __restrict__ deg,
                                                    const int* __restrict__ part,
                                                    int* __restrict__ off) {
    int t = threadIdx.x, lane = t & 63, wv = t >> 6;
    size_t base = (size_t)blockIdx.x * 2048 + (size_t)t * 8;
    int v[8];
    int s = 0;
#pragma unroll
    for (int j = 0; j < 8; j++) { v[j] = deg[base + j]; s += v[j]; }
    int incl = s;
    for (int d = 1; d < 64; d <<= 1) {
        int o = __shfl_up(incl, d, 64);
        if (lane >= d) incl += o;
    }
    __shared__ int wsum[4];
    if (lane == 63) wsum[wv] = incl;
    __syncthreads();
    int pre = part[blockIdx.x] + (incl - s);
    for (int w = 0; w < wv; w++) pre += wsum[w];
#pragma unroll
    for (int j = 0; j < 8; j++) { off[base + j] = pre; pre += v[j]; }
    if (blockIdx.x == gridDim.x - 1 && t == 255) off[base + 8] = pre;  // off[NP]
}

__global__ __launch_bounds__(256) void fill_kernel(const int* __restrict__ ei, int E, int N,
                                                   const int* __restrict__ mode,
                                                   const int* __restrict__ off,
                                                   int* __restrict__ cur,
                                                   int* __restrict__ sorted) {
    int i = blockIdx.x * 256 + threadIdx.x;
    if (i >= E) return;
    int m64 = mode[0];
    int s = m64 ? ei[2 * i] : ei[i];
    int d = m64 ? ei[2 * E + 2 * i] : ei[E + i];
    if ((unsigned)d >= (unsigned)N) return;
    if ((unsigned)s >= (unsigned)N) s = 0;
    int p = atomicAdd(&cur[d], 1);
    int pos = off[d] + p;
    if ((unsigned)pos < (unsigned)E) sorted[pos] = s;
}

// ---------------- weight transpose into bf16 T ----------------
// T layout: [0]=Wp^T [16384]=Wl0^T [32768]=Wr0^T [49152]=Wl1^T [65536]=Wr1^T [81920]=Ws1^T(64x128)
__global__ __launch_bounds__(256) void prep_kernel(const void* __restrict__ Wp, const void* __restrict__ Wl0,
                                                   const void* __restrict__ Wr0, const void* __restrict__ Wl1,
                                                   const void* __restrict__ Wr1, const void* __restrict__ Ws1,
                                                   const int* __restrict__ mode, u16* __restrict__ T) {
    int idx = blockIdx.x * 256 + threadIdx.x;
    int f32 = mode[1];
    if (idx < 81920) {
        int m = idx >> 14, e = idx & 16383, n = e & 127, k = e >> 7;
        const void* s;
        switch (m) {
            case 0: s = Wp; break;
            case 1: s = Wl0; break;
            case 2: s = Wr0; break;
            case 3: s = Wl1; break;
            default: s = Wr1; break;
        }
        float v = ldf(s, e, f32);
        T[m * 16384 + n * 128 + k] = f2b(v);
    } else if (idx < 90112) {
        int e = idx - 81920, k = e >> 6, n = e & 63;
        T[81920 + n * 128 + k] = f2b(ldf(Ws1, e, f32));
    }
}

// ---------------- aggregation: mean over CSR neighbors ----------------
__device__ __forceinline__ void acc8(float* acc, uint4 v) {
    acc[0] += b2f((u16)v.x); acc[1] += b2f((u16)(v.x >> 16));
    acc[2] += b2f((u16)v.y); acc[3] += b2f((u16)(v.y >> 16));
    acc[4] += b2f((u16)v.z); acc[5] += b2f((u16)(v.z >> 16));
    acc[6] += b2f((u16)v.w); acc[7] += b2f((u16)(v.w >> 16));
}

__global__ __launch_bounds__(256) void agg_kernel(const void* __restrict__ Hv, const int* __restrict__ off,
                                                  const int* __restrict__ srcs, u16* __restrict__ meanO,
                                                  int N, int E, const int* __restrict__ mode, int applyF32) {
    const int tid = threadIdx.x;
    const int node = blockIdx.x * 4 + (tid >> 6);
    if (node >= N) return;
    const int lane = tid & 63;
    int s0 = off[node], s1 = off[node + 1];
    if (s0 < 0) s0 = 0;
    if (s1 > E) s1 = E;
    if (s1 < s0) s1 = s0;
    const int dg = s1 - s0;
    const float inv = 1.f / (float)(dg > 1 ? dg : 1);
    const int f32 = applyF32 ? mode[1] : 0;
    if (!f32) {
        const u16* H = (const u16*)Hv;
        const int sub = lane >> 4, m = lane & 15;
        float acc[8];
#pragma unroll
        for (int d = 0; d < 8; d++) acc[d] = 0.f;
        for (int e = s0; e < s1; e += 8) {
            int ee0 = e + sub, ee1 = ee0 + 4;
            bool ok0 = ee0 < s1, ok1 = ee1 < s1;
            int i0 = srcs[ok0 ? ee0 : s0];
            int i1 = srcs[ok1 ? ee1 : s0];
            if ((unsigned)i0 >= (unsigned)N) i0 = 0;
            if ((unsigned)i1 >= (unsigned)N) i1 = 0;
            uint4 v0 = *(const uint4*)(H + (size_t)i0 * 128 + m * 8);
            uint4 v1 = *(const uint4*)(H + (size_t)i1 * 128 + m * 8);
            if (ok0) acc8(acc, v0);
            if (ok1) acc8(acc, v1);
        }
#pragma unroll
        for (int d = 0; d < 8; d++) {
            acc[d] += __shfl_xor(acc[d], 16, 64);
            acc[d] += __shfl_xor(acc[d], 32, 64);
        }
        if (sub == 0) {
            uint4 o;
            o.x = (u32)f2b(acc[0] * inv) | ((u32)f2b(acc[1] * inv) << 16);
            o.y = (u32)f2b(acc[2] * inv) | ((u32)f2b(acc[3] * inv) << 16);
            o.z = (u32)f2b(acc[4] * inv) | ((u32)f2b(acc[5] * inv) << 16);
            o.w = (u32)f2b(acc[6] * inv) | ((u32)f2b(acc[7] * inv) << 16);
            *(uint4*)(meanO + (size_t)node * 128 + m * 8) = o;
        }
    } else {
        const float* Hf = (const float*)Hv;
        int col = lane * 2;
        float r0 = 0.f, r1 = 0.f;
        for (int e = s0; e < s1; ++e) {
            int iA = srcs[e];
            if ((unsigned)iA >= (unsigned)N) iA = 0;
            const float* p = Hf + (size_t)iA * 128 + col;
            r0 += p[0]; r1 += p[1];
        }
        *(u32*)(meanO + (size_t)node * 128 + col) = (u32)f2b(r0 * inv) | ((u32)f2b(r1 * inv) << 16);
    }
}

// ---------------- MFMA GEMM pieces ----------------
// A row-major [row][k], WT bf16 [n][k]; wave: 32 rows x 128 cols; acc = 64 regs.
// F32 is a COMPILE-TIME dtype switch: hot path (F32=0) is branch-free so loads batch.
template <int F32>
__device__ __forceinline__ void mm_prod(const void* __restrict__ A, const u16* __restrict__ WT,
                                        long rowBase, int N, int m0, int q, f32x4 acc[2][8]) {
#pragma unroll
    for (int ks = 0; ks < 4; ++ks) {
        const int k = ks * 32 + q * 8;
        short8 bf[8];
#pragma unroll
        for (int n = 0; n < 8; n++) bf[n] = *(const short8*)(WT + (n * 16 + m0) * 128 + k);
#pragma unroll
        for (int r = 0; r < 2; r++) {
            long row = rowBase + r * 16 + m0;
            if (row >= N) row = N - 1;
            short8 a;
            if (!F32) {
                a = *(const short8*)((const u16*)A + (size_t)row * 128 + k);
            } else {
                const float* f = (const float*)A + (size_t)row * 128 + k;
#pragma unroll
                for (int j = 0; j < 8; j++) a[j] = (short)f2b(f[j]);
            }
#pragma unroll
            for (int n = 0; n < 8; n++)
                acc[r][n] = __builtin_amdgcn_mfma_f32_16x16x32_bf16(a, bf[n], acc[r][n], 0, 0, 0);
        }
    }
}

// h0 = x@Wp + bp   (residual pass; one acc set -> 4 waves/SIMD)
template <int F32>
__global__ __launch_bounds__(256, 4) void gemmR_kernel(const void* __restrict__ x, const u16* __restrict__ WTp,
                                                       const void* __restrict__ bp, const int* __restrict__ mode,
                                                       u16* __restrict__ h0, int N) {
    if (mode[1] != F32) return;  // uniform early-exit; twin variant handles the other dtype
    const int lane = threadIdx.x & 63, wave = threadIdx.x >> 6;
    const int m0 = lane & 15, q = lane >> 4;
    const long rowBase = (long)blockIdx.x * 128 + wave * 32;
    f32x4 acc[2][8];
#pragma unroll
    for (int r = 0; r < 2; r++)
#pragma unroll
        for (int n = 0; n < 8; n++) acc[r][n] = {0.f, 0.f, 0.f, 0.f};
    mm_prod<F32>(x, WTp, rowBase, N, m0, q, acc);
#pragma unroll
    for (int r = 0; r < 2; r++)
#pragma unroll
        for (int n = 0; n < 8; n++) {
            int col = n * 16 + m0;
            float bpv = ldf(bp, col, F32);
#pragma unroll
            for (int g = 0; g < 4; g++) {
                long row = rowBase + r * 16 + q * 4 + g;
                if (row < N) h0[(size_t)row * 128 + col] = f2b(acc[r][n][g] + bpv);
            }
        }
}

// h0 = gelu(mean@Wl0 + x@Wr0 + bl0) + h0   (in-place residual: same-lane read-then-write)
template <int F32>
__global__ __launch_bounds__(256, 4) void gemmU0_kernel(const void* __restrict__ x, const u16* __restrict__ mean,
                                                        const u16* __restrict__ WTl, const u16* __restrict__ WTr,
                                                        const void* __restrict__ bl, const int* __restrict__ mode,
                                                        u16* __restrict__ h0, int N) {
    if (mode[1] != F32) return;
    const int lane = threadIdx.x & 63, wave = threadIdx.x >> 6;
    const int m0 = lane & 15, q = lane >> 4;
    const long rowBase = (long)blockIdx.x * 128 + wave * 32;
    f32x4 acc[2][8];
#pragma unroll
    for (int r = 0; r < 2; r++)
#pragma unroll
        for (int n = 0; n < 8; n++) acc[r][n] = {0.f, 0.f, 0.f, 0.f};
    mm_prod<0>(mean, WTl, rowBase, N, m0, q, acc);
    mm_prod<F32>(x, WTr, rowBase, N, m0, q, acc);
#pragma unroll
    for (int r = 0; r < 2; r++)
#pragma unroll
        for (int n = 0; n < 8; n++) {
            int col = n * 16 + m0;
            float blv = ldf(bl, col, F32);
#pragma unroll
            for (int g = 0; g < 4; g++) {
                long row = rowBase + r * 16 + q * 4 + g;
                if (row < N) {
                    size_t idx = (size_t)row * 128 + col;
                    float res = b2f(h0[idx]);
                    h0[idx] = f2b(gelu_f(acc[r][n][g] + blv) + res);
                }
            }
        }
}

// h1 = gelu(mean1@Wl1 + h0@Wr1 + bl1) + h0   (mean/h1 alias safe: wave-private rows)
__global__ __launch_bounds__(256, 4) void gemm1_kernel(const u16* __restrict__ h0, const u16* mean,
                                                       const u16* __restrict__ WTl, const u16* __restrict__ WTr,
                                                       const void* __restrict__ bl, const int* __restrict__ mode,
                                                       u16* h1, int N) {
    const int lane = threadIdx.x & 63, wave = threadIdx.x >> 6;
    const int m0 = lane & 15, q = lane >> 4;
    const int f32 = mode[1];
    const long rowBase = (long)blockIdx.x * 128 + wave * 32;
    f32x4 acc[2][8];
#pragma unroll
    for (int r = 0; r < 2; r++)
#pragma unroll
        for (int n = 0; n < 8; n++) acc[r][n] = {0.f, 0.f, 0.f, 0.f};
    mm_prod<0>(mean, WTl, rowBase, N, m0, q, acc);
    mm_prod<0>(h0, WTr, rowBase, N, m0, q, acc);
#pragma unroll
    for (int r = 0; r < 2; r++)
#pragma unroll
        for (int n = 0; n < 8; n++) {
            int col = n * 16 + m0;
            float blv = ldf(bl, col, f32);
#pragma unroll
            for (int g = 0; g < 4; g++) {
                long row = rowBase + r * 16 + q * 4 + g;
                if (row < N) {
                    size_t idx = (size_t)row * 128 + col;
                    float res = b2f(h0[idx]);
                    h1[idx] = f2b(gelu_f(acc[r][n][g] + blv) + res);
                }
            }
        }
}

// out = alpha*rr + (1-alpha)*(gelu(h1@Ws1+bs1)@Ws2 + bs2)
__global__ __launch_bounds__(256, 4) void score_kernel(const u16* __restrict__ h1, const u16* __restrict__ WTs,
                                                       const void* __restrict__ bs1, const void* __restrict__ w2,
                                                       const void* __restrict__ bs2, const void* __restrict__ rr,
                                                       const void* __restrict__ alpha_p, const int* __restrict__ mode,
                                                       void* __restrict__ out, int N) {
    const int lane = threadIdx.x & 63, wave = threadIdx.x >> 6;
    const int m0 = lane & 15, q = lane >> 4;
    const int f32 = mode[1];
    const long rowBase = (long)blockIdx.x * 128 + wave * 32;
    f32x4 acc[2][4];
#pragma unroll
    for (int r = 0; r < 2; r++)
#pragma unroll
        for (int n = 0; n < 4; n++) acc[r][n] = {0.f, 0.f, 0.f, 0.f};
#pragma unroll
    for (int ks = 0; ks < 4; ++ks) {
        const int k = ks * 32 + q * 8;
        short8 bf[4];
#pragma unroll
        for (int n = 0; n < 4; n++) bf[n] = *(const short8*)(WTs + (n * 16 + m0) * 128 + k);
#pragma unroll
        for (int r = 0; r < 2; r++) {
            long row = rowBase + r * 16 + m0;
            if (row >= N) row = N - 1;
            short8 a = *(const short8*)(h1 + (size_t)row * 128 + k);
#pragma unroll
            for (int n = 0; n < 4; n++)
                acc[r][n] = __builtin_amdgcn_mfma_f32_16x16x32_bf16(a, bf[n], acc[r][n], 0, 0, 0);
        }
    }
    float alpha = 1.f / (1.f + expf(-ldf(alpha_p, 0, f32)));
    float bs2v = ldf(bs2, 0, f32);
    float w2v[4], b1v[4];
#pragma unroll
    for (int n = 0; n < 4; n++) {
        int col = n * 16 + m0;
        w2v[n] = ldf(w2, col, f32);
        b1v[n] = ldf(bs1, col, f32);
    }
#pragma unroll
    for (int r = 0; r < 2; r++) {
        float s[4] = {0.f, 0.f, 0.f, 0.f};
#pragma unroll
        for (int n = 0; n < 4; n++)
#pragma unroll
            for (int g = 0; g < 4; g++) s[g] += gelu_f(acc[r][n][g] + b1v[n]) * w2v[n];
#pragma unroll
        for (int g = 0; g < 4; g++) {
            s[g] += __shfl_xor(s[g], 1, 64);
            s[g] += __shfl_xor(s[g], 2, 64);
            s[g] += __shfl_xor(s[g], 4, 64);
            s[g] += __shfl_xor(s[g], 8, 64);
        }
        if (m0 == 0) {
            long row0 = rowBase + r * 16 + q * 4;
#pragma unroll
            for (int g = 0; g < 4; g++) {
                long row = row0 + g;
                if (row < N) {
                    float sc = s[g] + bs2v;
                    float v = alpha * ldf(rr, (int)row, f32) + (1.f - alpha) * sc;
                    if (f32) ((float*)out)[row] = v; else ((u16*)out)[row] = f2b(v);
                }
            }
        }
    }
}

extern "C" void kernel_launch(void* const* d_in, const int* in_sizes, int n_in,
                              void* d_out, int out_size, void* d_ws, size_t ws_size,
                              hipStream_t stream) {
    const void* x = d_in[0];
    const int* ei = (const int*)d_in[1];
    const void* rr = d_in[2];
    const void* Wp = d_in[3];
    const void* bp = d_in[4];
    const void* Wl0 = d_in[5];
    const void* bl0 = d_in[6];
    const void* Wr0 = d_in[7];
    const void* Wl1 = d_in[8];
    const void* bl1 = d_in[9];
    const void* Wr1 = d_in[10];
    const void* Ws1 = d_in[11];
    const void* bs1 = d_in[12];
    const void* Ws2 = d_in[13];
    const void* bs2 = d_in[14];
    const void* alpha = d_in[15];

    const int N = in_sizes[0] / 128;
    const int E = in_sizes[1] / 2;
    const int NP = ((N + 2047) / 2048) * 2048;
    const int NB = NP / 2048;

    char* w = (char*)d_ws;
    size_t used = 0;
    auto alloc = [&](size_t b) { char* p = w + used; used += (b + 255) & ~(size_t)255; return p; };
    int* mode = (int*)alloc(256);
    int* deg = (int*)alloc((size_t)NP * 4);
    int* cursor = (int*)alloc((size_t)NP * 4);   // contiguous with deg
    int* off = (int*)alloc((size_t)(NP + 64) * 4);
    int* part = (int*)alloc(64 * 4);
    int* sorted = (int*)alloc((size_t)E * 4);
    u16* T = (u16*)alloc(90112 * 2);
    u16* meanb = (u16*)alloc((size_t)NP * 128 * 2);
    u16* h0 = (u16*)alloc((size_t)NP * 128 * 2);
    u16* h1 = meanb;  // alias: gemm1 waves read/write only their own 32-row slices

    if (ws_size < 4096) {
        fallback_kernel<<<(N + 255) / 256, 256, 0, stream>>>(rr, alpha, nullptr, d_out, N);
        return;
    }
    probe_kernel<<<1, 64, 0, stream>>>(ei, (const u16*)x, mode);
    if (used > ws_size) {
        fallback_kernel<<<(N + 255) / 256, 256, 0, stream>>>(rr, alpha, mode, d_out, N);
        return;
    }

    hipMemsetAsync(deg, 0, (size_t)NP * 4 * 2, stream);      // deg + cursor

    prep_kernel<<<(90112 + 255) / 256, 256, 0, stream>>>(Wp, Wl0, Wr0, Wl1, Wr1, Ws1, mode, T);
    hist_kernel<<<(E + 255) / 256, 256, 0, stream>>>(ei, E, N, mode, deg);
    scanA_kernel<<<NB, 256, 0, stream>>>(deg, part);
    scanB_kernel<<<1, 64, 0, stream>>>(part, NB);
    scanC_kernel<<<NB, 256, 0, stream>>>(deg, part, off);
    fill_kernel<<<(E + 255) / 256, 256, 0, stream>>>(ei, E, N, mode, off, cursor, sorted);

    const int gemmGrid = (N + 127) / 128;
    const int aggGrid = (N + 3) / 4;

    // residual pass (both dtype variants; one no-ops)
    gemmR_kernel<0><<<gemmGrid, 256, 0, stream>>>(x, T + 0, bp, mode, h0, N);
    gemmR_kernel<1><<<gemmGrid, 256, 0, stream>>>(x, T + 0, bp, mode, h0, N);

    agg_kernel<<<aggGrid, 256, 0, stream>>>(x, off, sorted, meanb, N, E, mode, 1);

    gemmU0_kernel<0><<<gemmGrid, 256, 0, stream>>>(x, meanb, T + 16384, T + 32768, bl0, mode, h0, N);
    gemmU0_kernel<1><<<gemmGrid, 256, 0, stream>>>(x, meanb, T + 16384, T + 32768, bl0, mode, h0, N);

    agg_kernel<<<aggGrid, 256, 0, stream>>>(h0, off, sorted, meanb, N, E, mode, 0);
    gemm1_kernel<<<gemmGrid, 256, 0, stream>>>(h0, meanb, T + 49152, T + 65536, bl1, mode, h1, N);
    score_kernel<<<gemmGrid, 256, 0, stream>>>(h1, T + 81920, bs1, Ws2, bs2, rr, alpha, mode, d_out, N);
}